// Round 1
// baseline (935.679 us; speedup 1.0000x reference)
//
#include <hip/hip_runtime.h>

// GRU fused kernel: B=128, S=144, T=50, I=10, H=64, O=1.
// Grid = T * (B/BT) = 50*4 = 200 workgroups, 256 threads each.
// Each wg owns one turbine t and a 32-row batch tile; runs the full S=144
// forward scan with Whh/Wih/biases/h staged in LDS, then the 1-step backward
// cell (h0=0 => Whh_b unused) and the FC epilogue.

constexpr int B_N = 128, S_N = 144, T_N = 50, I_N = 10, H_N = 64, G3_N = 192;
constexpr int BT  = 32;            // batch rows per workgroup
constexpr int NB  = B_N / BT;      // 4 batch tiles
constexpr int WST = 68;            // LDS stride for [.][64] tiles (pad +4)
constexpr int XST = 12;            // x / Wih padded to 12 (10 real + 2 zero)
constexpr int PST = 257;           // pre-activation LDS stride (odd -> 2-way max)

__device__ __forceinline__ float fsig(float v)  { return 1.0f / (1.0f + __expf(-v)); }
__device__ __forceinline__ float ftanh(float v) { return 1.0f - 2.0f / (__expf(2.0f * v) + 1.0f); }

__global__ __launch_bounds__(256, 1)
void gru_fused(const float* __restrict__ x,
               const float* __restrict__ Wih_f, const float* __restrict__ Whh_f,
               const float* __restrict__ bih_f, const float* __restrict__ bhh_f,
               const float* __restrict__ Wih_b, const float* __restrict__ bih_b,
               const float* __restrict__ bhh_b,
               const float* __restrict__ Wfc,   const float* __restrict__ bfc,
               float* __restrict__ out)
{
    __shared__ float Whh_l[G3_N * WST];   // 52.2 KB
    __shared__ float Wih_l[G3_N * XST];   //  9.2 KB
    __shared__ float bih_l[G3_N];
    __shared__ float bhh_l[G3_N];
    __shared__ float h_l[BT * WST];       //  8.7 KB
    __shared__ float x_l[BT * XST];       //  1.5 KB
    __shared__ float pre_l[BT * PST];     // 32.9 KB   layout per row:
                                          // [0..127] r,z combined pre; [128..191] gh_n+bhh_n; [192..255] gi_n+bih_n

    const int tid = threadIdx.x;
    const int wg  = blockIdx.x;
    const int t   = wg / NB;
    const int b0  = (wg % NB) * BT;

    // ---- one-time staging ----
    {
        const float* whh = Whh_f + (size_t)t * G3_N * H_N;
        for (int idx = tid; idx < G3_N * H_N / 4; idx += 256) {      // 3072 float4
            const int g = idx >> 4, kc = idx & 15;
            const float4 v = reinterpret_cast<const float4*>(whh)[idx];
            *reinterpret_cast<float4*>(&Whh_l[g * WST + kc * 4]) = v;
        }
        const float* wih = Wih_f + (size_t)t * G3_N * I_N;
        for (int idx = tid; idx < G3_N * XST; idx += 256) {
            const int g = idx / XST, c = idx - g * XST;
            Wih_l[idx] = (c < I_N) ? wih[g * I_N + c] : 0.0f;
        }
        for (int g = tid; g < G3_N; g += 256) {
            bih_l[g] = bih_f[t * G3_N + g];
            bhh_l[g] = bhh_f[t * G3_N + g];
        }
        for (int idx = tid; idx < BT * WST; idx += 256) h_l[idx] = 0.0f;
    }

    const int gg = tid & 31;   // gate group: gates gg + 32*i, i=0..5
    const int rg = tid >> 5;   // row group:  rows  rg*4 + j,  j=0..3

    for (int s = 0; s < S_N; ++s) {
        // stage x[:, s, t, :] for this batch tile (padded to 12)
        for (int idx = tid; idx < BT * XST; idx += 256) {
            const int r = idx / XST, c = idx - r * XST;
            float v = 0.0f;
            if (c < I_N) v = x[((size_t)((b0 + r) * S_N + s) * T_N + t) * I_N + c];
            x_l[idx] = v;
        }
        __syncthreads();   // x ready; h updates from previous step visible

        // ---- phase A: gh = Whh . h (dot-64) and gi = Wih . x (dot-12), 4 rows x 6 gates per thread ----
        float acc[4][6], accx[4][6];
        #pragma unroll
        for (int j = 0; j < 4; ++j)
            #pragma unroll
            for (int i = 0; i < 6; ++i) { acc[j][i] = 0.0f; accx[j][i] = 0.0f; }

        #pragma unroll 4
        for (int kc = 0; kc < 16; ++kc) {
            float4 hv[4], wv[6];
            #pragma unroll
            for (int j = 0; j < 4; ++j)
                hv[j] = *reinterpret_cast<const float4*>(&h_l[(rg * 4 + j) * WST + kc * 4]);
            #pragma unroll
            for (int i = 0; i < 6; ++i)
                wv[i] = *reinterpret_cast<const float4*>(&Whh_l[(gg + 32 * i) * WST + kc * 4]);
            #pragma unroll
            for (int j = 0; j < 4; ++j)
                #pragma unroll
                for (int i = 0; i < 6; ++i)
                    acc[j][i] += hv[j].x * wv[i].x + hv[j].y * wv[i].y
                               + hv[j].z * wv[i].z + hv[j].w * wv[i].w;
        }
        #pragma unroll
        for (int kc = 0; kc < 3; ++kc) {
            float4 xv[4], wv[6];
            #pragma unroll
            for (int j = 0; j < 4; ++j)
                xv[j] = *reinterpret_cast<const float4*>(&x_l[(rg * 4 + j) * XST + kc * 4]);
            #pragma unroll
            for (int i = 0; i < 6; ++i)
                wv[i] = *reinterpret_cast<const float4*>(&Wih_l[(gg + 32 * i) * XST + kc * 4]);
            #pragma unroll
            for (int j = 0; j < 4; ++j)
                #pragma unroll
                for (int i = 0; i < 6; ++i)
                    accx[j][i] += xv[j].x * wv[i].x + xv[j].y * wv[i].y
                                + xv[j].z * wv[i].z + xv[j].w * wv[i].w;
        }

        #pragma unroll
        for (int j = 0; j < 4; ++j) {
            const int row = rg * 4 + j;
            #pragma unroll
            for (int i = 0; i < 6; ++i) {
                const int g = gg + 32 * i;
                if (i < 4) {  // r,z gates: gi and gh combine
                    pre_l[row * PST + g] = acc[j][i] + accx[j][i] + bih_l[g] + bhh_l[g];
                } else {      // n gates: keep hidden / input parts separate
                    pre_l[row * PST + g]      = acc[j][i]  + bhh_l[g];
                    pre_l[row * PST + g + 64] = accx[j][i] + bih_l[g];
                }
            }
        }
        __syncthreads();   // pre ready; all phase-A reads of h/x done

        // ---- phase B: gates + h update; 8 units (one row, 8 cols) per thread ----
        {
            const int row2 = tid >> 3;
            const int j0   = (tid & 7) * 8;
            float hn[8];
            #pragma unroll
            for (int m = 0; m < 8; ++m) {
                const int j   = j0 + m;
                const float r  = fsig(pre_l[row2 * PST + j]);
                const float z  = fsig(pre_l[row2 * PST + 64 + j]);
                const float nn = ftanh(pre_l[row2 * PST + 192 + j] + r * pre_l[row2 * PST + 128 + j]);
                const float ho = h_l[row2 * WST + j];
                hn[m] = nn + z * (ho - nn);
            }
            #pragma unroll
            for (int m = 0; m < 8; ++m) h_l[row2 * WST + j0 + m] = hn[m];
        }
        // no barrier here: next iteration's x-stage doesn't touch h/pre,
        // and its __syncthreads() orders h writes before phase A reads.
    }

    __syncthreads();   // final h visible to all; pre_l free for reuse

    // ---- backward cell (single step, h0 = 0 => gh = bhh_b) on x[:, S-1, :] (still in x_l) ----
    {
        const int row2 = tid >> 3;
        const int j0   = (tid & 7) * 8;
        const float* wib = Wih_b + (size_t)t * G3_N * I_N;
        const float* bib = bih_b + t * G3_N;
        const float* bhb = bhh_b + t * G3_N;
        float xr[I_N];
        #pragma unroll
        for (int k = 0; k < I_N; ++k) xr[k] = x_l[row2 * XST + k];
        float hbv[8];
        #pragma unroll
        for (int m = 0; m < 8; ++m) {
            const int j = j0 + m;
            float ir = bib[j], iz = bib[64 + j], inn = bib[128 + j];
            #pragma unroll
            for (int k = 0; k < I_N; ++k) {
                const float xv = xr[k];
                ir  += wib[(j)       * I_N + k] * xv;
                iz  += wib[(64 + j)  * I_N + k] * xv;
                inn += wib[(128 + j) * I_N + k] * xv;
            }
            const float r  = fsig(ir + bhb[j]);
            const float z  = fsig(iz + bhb[64 + j]);
            const float nn = ftanh(inn + r * bhb[128 + j]);
            hbv[m] = (1.0f - z) * nn;   // h0 = 0
        }
        #pragma unroll
        for (int m = 0; m < 8; ++m) pre_l[row2 * PST + j0 + m] = hbv[m];
    }
    __syncthreads();

    // ---- FC epilogue: out[b,0,t] = [hf|hb] . Wfc[t,0,:] + bfc[t] ----
    if (tid < BT) {
        const float* wfc = Wfc + (size_t)t * 2 * H_N;
        float acc = bfc[t];
        #pragma unroll 4
        for (int j = 0; j < H_N; ++j) acc += h_l[tid * WST + j]   * wfc[j];
        #pragma unroll 4
        for (int j = 0; j < H_N; ++j) acc += pre_l[tid * PST + j] * wfc[64 + j];
        out[(size_t)(b0 + tid) * T_N + t] = acc;
    }
}

extern "C" void kernel_launch(void* const* d_in, const int* in_sizes, int n_in,
                              void* d_out, int out_size, void* d_ws, size_t ws_size,
                              hipStream_t stream) {
    const float* x     = (const float*)d_in[0];
    const float* Wih_f = (const float*)d_in[1];
    const float* Whh_f = (const float*)d_in[2];
    const float* bih_f = (const float*)d_in[3];
    const float* bhh_f = (const float*)d_in[4];
    const float* Wih_b = (const float*)d_in[5];
    // d_in[6] = Whh_b: unused (backward cell runs one step from h0 == 0,
    // so its hidden contribution reduces to bhh_b alone).
    const float* bih_b = (const float*)d_in[7];
    const float* bhh_b = (const float*)d_in[8];
    const float* Wfc   = (const float*)d_in[9];
    const float* bfc   = (const float*)d_in[10];
    float* out = (float*)d_out;

    dim3 grid(T_N * NB), block(256);
    hipLaunchKernelGGL(gru_fused, grid, block, 0, stream,
                       x, Wih_f, Whh_f, bih_f, bhh_f, Wih_b, bih_b, bhh_b, Wfc, bfc, out);
}

// Round 2
// 194.738 us; speedup vs baseline: 4.8048x; 4.8048x over previous
//
#include <hip/hip_runtime.h>

// GRU via MFMA: B=128, S=144, T=50, I=10, H=64, O=1.
// Grid = T * (B/32) = 200 wgs x 512 threads (8 waves).
// Each wg: turbine t, 32-row batch tile. Per step, gh+gi+bias computed as
// f16 MFMAs (weights resident in VGPRs), gates + h-update in registers,
// h round-trips through double-buffered f16 LDS (one barrier/step).
//
// Wave w: row-block rb=w>>2 (16 rows), unit cols uc=(w&3)*16.
// Tiles: r-gates [uc..uc+16), z-gates [64+uc..), n-gates [128+uc..).
// MFMA 16x16x32 layouts (gfx950): A: m=lane&15, k=(lane>>4)*8+elem;
// B: n=lane&15, same k-map; D: col=lane&15, row=(lane>>4)*4+reg (m89-verified).

typedef _Float16 f16;
typedef _Float16 f16x8 __attribute__((ext_vector_type(8)));
typedef float    f32x4 __attribute__((ext_vector_type(4)));

constexpr int B_N = 128, S_N = 144, T_N = 50, I_N = 10, H_N = 64, G3 = 192;
constexpr int BT = 32, NB = B_N / BT;   // batch tile, tiles per turbine
constexpr int HST = 88;                 // f16 elems per h row -> 176B (16B-aligned, spreads banks)
constexpr int XST = 40;                 // f16 slots per x row -> 80B   (slots: 0-9 x, 10 = 1.0, 11-31 zero, 32-39 pad)

#define MFMA16(a, b, c) __builtin_amdgcn_mfma_f32_16x16x32_f16((a), (b), (c), 0, 0, 0)

__device__ __forceinline__ float fsig(float v)  { return 1.0f / (1.0f + __expf(-v)); }
__device__ __forceinline__ float ftanh(float v) { return 1.0f - 2.0f / (__expf(2.0f * v) + 1.0f); }

__global__ __launch_bounds__(512, 1)
void gru_mfma(const float* __restrict__ x,
              const float* __restrict__ Wih_f, const float* __restrict__ Whh_f,
              const float* __restrict__ bih_f, const float* __restrict__ bhh_f,
              const float* __restrict__ Wih_b, const float* __restrict__ bih_b,
              const float* __restrict__ bhh_b,
              const float* __restrict__ Wfc,   const float* __restrict__ bfc,
              float* __restrict__ out)
{
    __shared__ f16  hL[2][BT][HST];          // 11.3 KB, double-buffered h (f16)
    __shared__ f16  xL[2][BT][XST];          //  5.1 KB, double-buffered x A-operand rows
    __shared__ float hfL[BT][H_N + 1];       //  8.3 KB, epilogue: forward h (f32)
    __shared__ float hbL[BT][H_N + 1];       //  8.3 KB, epilogue: backward h (f32)

    const int tid = threadIdx.x;
    const int w   = tid >> 6, l = tid & 63;
    const int rb  = w >> 2;            // row-block 0..1
    const int uc  = (w & 3) * 16;      // unit-col base 0,16,32,48
    const int lc  = l & 15;            // n (gate col) for B/D, m (row) for A
    const int lg  = l >> 4;            // k-group
    const int t   = blockIdx.x / NB;
    const int b0  = (blockIdx.x % NB) * BT;

    // ---------------- prologue ----------------
    // xL: zero everywhere except slot 10 = 1.0 (bias lane of the A operand)
    {
        f16* xp = &xL[0][0][0];
        for (int i = tid; i < 2 * BT * XST; i += 512) {
            const int c = i % XST;
            xp[i] = (c == 10) ? (f16)1.0f : (f16)0.0f;
        }
        f16* hp = &hL[0][0][0];
        for (int i = tid; i < BT * HST; i += 512) hp[i] = (f16)0.0f;   // h0 = 0
    }
    // stage x for s=0
    const int pr = tid / I_N, pc = tid - pr * I_N;   // valid when tid < 320
    if (tid < BT * I_N)
        xL[0][pr][pc] = (f16)x[(((size_t)(b0 + pr) * S_N + 0) * T_N + t) * I_N + pc];

    // weight fragments, resident in registers for the whole scan
    const float* Whh = Whh_f + (size_t)t * G3 * H_N;
    const float* Wih = Wih_f + (size_t)t * G3 * I_N;

    auto loadBh = [&](int g, int kk) -> f16x8 {
        const float4* p = (const float4*)(Whh + (size_t)g * H_N + kk * 32 + lg * 8);
        const float4 a = p[0], b = p[1];
        f16x8 v;
        v[0] = (f16)a.x; v[1] = (f16)a.y; v[2] = (f16)a.z; v[3] = (f16)a.w;
        v[4] = (f16)b.x; v[5] = (f16)b.y; v[6] = (f16)b.z; v[7] = (f16)b.w;
        return v;
    };
    auto loadBx = [&](int g, bool rz) -> f16x8 {
        f16x8 v;
        #pragma unroll
        for (int j = 0; j < 8; ++j) {
            const int k = lg * 8 + j;
            float val = 0.0f;
            if (k < I_N)       val = Wih[(size_t)g * I_N + k];
            else if (k == 10)  val = bih_f[t * G3 + g] + (rz ? bhh_f[t * G3 + g] : 0.0f);
            v[j] = (f16)val;
        }
        return v;
    };

    const f16x8 BhR0 = loadBh(uc + lc, 0),       BhR1 = loadBh(uc + lc, 1);
    const f16x8 BhZ0 = loadBh(64 + uc + lc, 0),  BhZ1 = loadBh(64 + uc + lc, 1);
    const f16x8 BhN0 = loadBh(128 + uc + lc, 0), BhN1 = loadBh(128 + uc + lc, 1);
    const f16x8 BxR  = loadBx(uc + lc, true);
    const f16x8 BxZ  = loadBx(64 + uc + lc, true);
    const f16x8 BxN  = loadBx(128 + uc + lc, false);
    const float bnh  = bhh_f[t * G3 + 128 + uc + lc];   // n-gate hidden bias (kept out of MFMA: multiplied by r)

    float ho0 = 0.f, ho1 = 0.f, ho2 = 0.f, ho3 = 0.f;   // this lane's 4 h values (rows rb*16+lg*4+j, col uc+lc)

    __syncthreads();

    // ---------------- scan ----------------
    for (int s = 0; s < S_N; ++s) {
        const int cur = s & 1, nxt = cur ^ 1;

        // prefetch next step's x (latency hidden under MFMA + gates)
        float pxf = 0.0f;
        const bool pld = (s + 1 < S_N) && (tid < BT * I_N);
        if (pld) pxf = x[(((size_t)(b0 + pr) * S_N + (s + 1)) * T_N + t) * I_N + pc];

        // A fragments from LDS
        const f16* hrow = &hL[cur][rb * 16 + lc][0];
        const f16x8 hA0 = *(const f16x8*)(hrow + lg * 8);
        const f16x8 hA1 = *(const f16x8*)(hrow + 32 + lg * 8);
        const f16x8 xA  = *(const f16x8*)(&xL[cur][rb * 16 + lc][lg * 8]);

        f32x4 aR  = {0.f, 0.f, 0.f, 0.f};
        f32x4 aZ  = {0.f, 0.f, 0.f, 0.f};
        f32x4 aNH = {0.f, 0.f, 0.f, 0.f};
        f32x4 aNX = {0.f, 0.f, 0.f, 0.f};
        aR  = MFMA16(xA,  BxR,  aR);   // gi_r + bih_r + bhh_r (bias via 1.0 slot)
        aZ  = MFMA16(xA,  BxZ,  aZ);
        aNX = MFMA16(xA,  BxN,  aNX);  // gi_n + bih_n
        aR  = MFMA16(hA0, BhR0, aR);
        aR  = MFMA16(hA1, BhR1, aR);
        aZ  = MFMA16(hA0, BhZ0, aZ);
        aZ  = MFMA16(hA1, BhZ1, aZ);
        aNH = MFMA16(hA0, BhN0, aNH);  // gh_n (bhh_n added below, inside r*(...))
        aNH = MFMA16(hA1, BhN1, aNH);

        // gates + h update, fully in registers (D: row=(l>>4)*4+j, col=lc)
        {
            const int r0 = rb * 16 + lg * 4;
            {
                const float rr = fsig(aR[0]), zz = fsig(aZ[0]);
                const float nn = ftanh(aNX[0] + rr * (aNH[0] + bnh));
                ho0 = nn + zz * (ho0 - nn);
                hL[nxt][r0 + 0][uc + lc] = (f16)ho0;
            }
            {
                const float rr = fsig(aR[1]), zz = fsig(aZ[1]);
                const float nn = ftanh(aNX[1] + rr * (aNH[1] + bnh));
                ho1 = nn + zz * (ho1 - nn);
                hL[nxt][r0 + 1][uc + lc] = (f16)ho1;
            }
            {
                const float rr = fsig(aR[2]), zz = fsig(aZ[2]);
                const float nn = ftanh(aNX[2] + rr * (aNH[2] + bnh));
                ho2 = nn + zz * (ho2 - nn);
                hL[nxt][r0 + 2][uc + lc] = (f16)ho2;
            }
            {
                const float rr = fsig(aR[3]), zz = fsig(aZ[3]);
                const float nn = ftanh(aNX[3] + rr * (aNH[3] + bnh));
                ho3 = nn + zz * (ho3 - nn);
                hL[nxt][r0 + 3][uc + lc] = (f16)ho3;
            }
        }

        if (pld) xL[nxt][pr][pc] = (f16)pxf;

        __syncthreads();   // next-step h + x visible; double-buffering removes the WAR barrier
    }

    // ---------------- epilogue ----------------
    // forward h (f32, from registers) -> LDS
    {
        const int r0 = rb * 16 + lg * 4;
        hfL[r0 + 0][uc + lc] = ho0;
        hfL[r0 + 1][uc + lc] = ho1;
        hfL[r0 + 2][uc + lc] = ho2;
        hfL[r0 + 3][uc + lc] = ho3;
    }

    // backward cell: single step from h0=0 (=> Whh_b unused), on x[:, S-1, :]
    {
        const int row2 = tid >> 4;          // 0..31
        const int j0   = (tid & 15) * 4;    // 4 units per thread
        const float* wib = Wih_b + (size_t)t * G3 * I_N;
        const float* bib = bih_b + t * G3;
        const float* bhb = bhh_b + t * G3;
        float xr[I_N];
        #pragma unroll
        for (int k = 0; k < I_N; ++k)
            xr[k] = x[(((size_t)(b0 + row2) * S_N + (S_N - 1)) * T_N + t) * I_N + k];
        #pragma unroll
        for (int m = 0; m < 4; ++m) {
            const int j = j0 + m;
            float ir = bib[j], iz = bib[64 + j], inn = bib[128 + j];
            #pragma unroll
            for (int k = 0; k < I_N; ++k) {
                const float xv = xr[k];
                ir  += wib[(size_t)j * I_N + k]          * xv;
                iz  += wib[(size_t)(64 + j) * I_N + k]   * xv;
                inn += wib[(size_t)(128 + j) * I_N + k]  * xv;
            }
            const float r  = fsig(ir + bhb[j]);
            const float z  = fsig(iz + bhb[64 + j]);
            const float nn = ftanh(inn + r * bhb[128 + j]);
            hbL[row2][j] = (1.0f - z) * nn;   // h0 = 0
        }
    }
    __syncthreads();

    // FC: out[b,0,t] = [hf|hb] . Wfc[t,0,:] + bfc[t]
    if (tid < BT) {
        const float* wfc = Wfc + (size_t)t * 2 * H_N;
        float acc = bfc[t];
        #pragma unroll 4
        for (int j = 0; j < H_N; ++j) acc += hfL[tid][j] * wfc[j];
        #pragma unroll 4
        for (int j = 0; j < H_N; ++j) acc += hbL[tid][j] * wfc[64 + j];
        out[(size_t)(b0 + tid) * T_N + t] = acc;
    }
}

extern "C" void kernel_launch(void* const* d_in, const int* in_sizes, int n_in,
                              void* d_out, int out_size, void* d_ws, size_t ws_size,
                              hipStream_t stream) {
    const float* x     = (const float*)d_in[0];
    const float* Wih_f = (const float*)d_in[1];
    const float* Whh_f = (const float*)d_in[2];
    const float* bih_f = (const float*)d_in[3];
    const float* bhh_f = (const float*)d_in[4];
    const float* Wih_b = (const float*)d_in[5];
    // d_in[6] = Whh_b: unused (backward cell runs one step from h0 == 0).
    const float* bih_b = (const float*)d_in[7];
    const float* bhh_b = (const float*)d_in[8];
    const float* Wfc   = (const float*)d_in[9];
    const float* bfc   = (const float*)d_in[10];
    float* out = (float*)d_out;

    dim3 grid(T_N * NB), block(512);
    hipLaunchKernelGGL(gru_mfma, grid, block, 0, stream,
                       x, Wih_f, Whh_f, bih_f, bhh_f, Wih_b, bih_b, bhh_b, Wfc, bfc, out);
}

// Round 3
// 180.984 us; speedup vs baseline: 5.1700x; 1.0760x over previous
//
#include <hip/hip_runtime.h>

// GRU via MFMA, round 3: B=128, S=144, T=50, I=10, H=64, O=1.
// Grid = T * (B/16) = 400 wgs x 256 threads (4 waves) -> all 256 CUs busy.
// Wave w owns gate-cols uc=w*16 for all 3 gates over the wg's 16 batch rows.
// Weights+biases resident in VGPRs; x prefetched 2 steps deep into registers;
// only h round-trips through double-buffered f16 LDS (one barrier/step).
// Gate nonlinearities via v_exp_f32 / v_rcp_f32 (1-ulp, ~3x cheaper than IEEE div).
//
// MFMA 16x16x32 f16 layouts (gfx950, m89-verified):
//   A: m=lane&15, k=(lane>>4)*8+e;  B: n=lane&15, same k-map;
//   D: col=lane&15, row=(lane>>4)*4+reg.

typedef _Float16 f16;
typedef _Float16 f16x8 __attribute__((ext_vector_type(8)));
typedef float    f32x4 __attribute__((ext_vector_type(4)));

constexpr int B_N = 128, S_N = 144, T_N = 50, I_N = 10, H_N = 64, G3 = 192;
constexpr int BT = 16, NB = B_N / BT;   // 8 batch tiles
constexpr int HST = 88;                 // f16/row -> 176B; rows 16B-aligned, 8 distinct bank slots, 2-way max (free)

#define MFMA16(a, b, c) __builtin_amdgcn_mfma_f32_16x16x32_f16((a), (b), (c), 0, 0, 0)

__device__ __forceinline__ float fsig(float v) {
    return __builtin_amdgcn_rcpf(1.0f + __builtin_amdgcn_exp2f(-1.44269504089f * v));
}
__device__ __forceinline__ float ftanh(float v) {
    return 1.0f - 2.0f * __builtin_amdgcn_rcpf(1.0f + __builtin_amdgcn_exp2f(2.88539008178f * v));
}

struct XSet { float2 p0, p1, p2, p3, p4; };   // p0..p3: x[0..7] (lg==0 lanes); p4: x[8..9] (lg==1 lanes)

__global__ __launch_bounds__(256, 1)
void gru_mfma(const float* __restrict__ x,
              const float* __restrict__ Wih_f, const float* __restrict__ Whh_f,
              const float* __restrict__ bih_f, const float* __restrict__ bhh_f,
              const float* __restrict__ Wih_b, const float* __restrict__ bih_b,
              const float* __restrict__ bhh_b,
              const float* __restrict__ Wfc,   const float* __restrict__ bfc,
              float* __restrict__ out)
{
    __shared__ f16   hL[2][BT][HST];        // 5.6 KB double-buffered h (f16)
    __shared__ float hfL[BT][H_N + 1];      // epilogue: forward h (f32)
    __shared__ float hbL[BT][H_N + 1];      // epilogue: backward h (f32)

    const int tid = threadIdx.x;
    const int w   = tid >> 6, l = tid & 63;
    const int uc  = w * 16;            // unit-col base 0,16,32,48
    const int lc  = l & 15;            // n (gate col) for B/D; m (batch row) for A
    const int lg  = l >> 4;            // k-group
    const int t   = blockIdx.x / NB;
    const int b0  = (blockIdx.x % NB) * BT;

    // ---------------- prologue ----------------
    {
        f16* hp = &hL[0][0][0];
        for (int i = tid; i < BT * HST; i += 256) hp[i] = (f16)0.0f;   // h0 = 0
    }

    // weight fragments, resident in registers for the whole scan
    const float* Whh = Whh_f + (size_t)t * G3 * H_N;
    const float* Wih = Wih_f + (size_t)t * G3 * I_N;

    auto loadBh = [&](int g, int kk) -> f16x8 {
        const float4* p = (const float4*)(Whh + (size_t)g * H_N + kk * 32 + lg * 8);
        const float4 a = p[0], b = p[1];
        f16x8 v;
        v[0] = (f16)a.x; v[1] = (f16)a.y; v[2] = (f16)a.z; v[3] = (f16)a.w;
        v[4] = (f16)b.x; v[5] = (f16)b.y; v[6] = (f16)b.z; v[7] = (f16)b.w;
        return v;
    };
    auto loadBx = [&](int g, bool rz) -> f16x8 {
        f16x8 v;
        #pragma unroll
        for (int j = 0; j < 8; ++j) {
            const int k = lg * 8 + j;
            float val = 0.0f;
            if (k < I_N)       val = Wih[(size_t)g * I_N + k];
            else if (k == 10)  val = bih_f[t * G3 + g] + (rz ? bhh_f[t * G3 + g] : 0.0f);
            v[j] = (f16)val;
        }
        return v;
    };

    const f16x8 BhR0 = loadBh(uc + lc, 0),       BhR1 = loadBh(uc + lc, 1);
    const f16x8 BhZ0 = loadBh(64 + uc + lc, 0),  BhZ1 = loadBh(64 + uc + lc, 1);
    const f16x8 BhN0 = loadBh(128 + uc + lc, 0), BhN1 = loadBh(128 + uc + lc, 1);
    const f16x8 BxR  = loadBx(uc + lc, true);
    const f16x8 BxZ  = loadBx(64 + uc + lc, true);
    const f16x8 BxN  = loadBx(128 + uc + lc, false);
    const float bnh  = bhh_f[t * G3 + 128 + uc + lc];   // n-gate hidden bias (applied inside r*(...))

    // x prefetch machinery (registers only; 8B loads are always aligned here)
    auto loadX = [&](int s, XSet& r) {
        const float* p = x + (((size_t)(b0 + lc) * S_N + s) * T_N + t) * I_N;
        if (lg == 0) {
            r.p0 = *(const float2*)(p);     r.p1 = *(const float2*)(p + 2);
            r.p2 = *(const float2*)(p + 4); r.p3 = *(const float2*)(p + 6);
        } else if (lg == 1) {
            r.p4 = *(const float2*)(p + 8);
        }
    };

    XSet xsA = {}, xsB = {};
    loadX(0, xsA);
    loadX(1, xsB);

    float ho0 = 0.f, ho1 = 0.f, ho2 = 0.f, ho3 = 0.f;   // lane's h: rows lg*4+j, col uc+lc

    __syncthreads();

    // ---------------- scan ----------------
    auto step = [&](int s, XSet& use) {
        const int cur = s & 1, nxt = cur ^ 1;

        // h A-fragments from LDS
        const f16* hrow = &hL[cur][lc][0];
        const f16x8 hA0 = *(const f16x8*)(hrow + lg * 8);
        const f16x8 hA1 = *(const f16x8*)(hrow + 32 + lg * 8);

        // x A-fragment from regs loaded 2 steps ago (slot k=10 carries the bias 1.0)
        f16x8 xA;
        #pragma unroll
        for (int e = 0; e < 8; ++e) xA[e] = (f16)0.0f;
        if (lg == 0) {
            xA[0] = (f16)use.p0.x; xA[1] = (f16)use.p0.y; xA[2] = (f16)use.p1.x; xA[3] = (f16)use.p1.y;
            xA[4] = (f16)use.p2.x; xA[5] = (f16)use.p2.y; xA[6] = (f16)use.p3.x; xA[7] = (f16)use.p3.y;
        } else if (lg == 1) {
            xA[0] = (f16)use.p4.x; xA[1] = (f16)use.p4.y; xA[2] = (f16)1.0f;
        }

        // issue prefetch for s+2 into the same set (read-before-write above)
        if (s + 2 < S_N) loadX(s + 2, use);

        f32x4 aR  = {0.f, 0.f, 0.f, 0.f};
        f32x4 aZ  = {0.f, 0.f, 0.f, 0.f};
        f32x4 aNH = {0.f, 0.f, 0.f, 0.f};
        f32x4 aNX = {0.f, 0.f, 0.f, 0.f};
        aR  = MFMA16(xA,  BxR,  aR);    // gi_r + b_r (both biases)
        aZ  = MFMA16(xA,  BxZ,  aZ);
        aNX = MFMA16(xA,  BxN,  aNX);   // gi_n + bih_n
        aR  = MFMA16(hA0, BhR0, aR);
        aR  = MFMA16(hA1, BhR1, aR);
        aZ  = MFMA16(hA0, BhZ0, aZ);
        aZ  = MFMA16(hA1, BhZ1, aZ);
        aNH = MFMA16(hA0, BhN0, aNH);   // gh_n
        aNH = MFMA16(hA1, BhN1, aNH);

        // gates + h update in registers (D: row=lg*4+j, col=lc)
        const int r0 = lg * 4;
        {
            const float rr = fsig(aR[0]), zz = fsig(aZ[0]);
            const float nn = ftanh(aNX[0] + rr * (aNH[0] + bnh));
            ho0 = nn + zz * (ho0 - nn);
            hL[nxt][r0 + 0][uc + lc] = (f16)ho0;
        }
        {
            const float rr = fsig(aR[1]), zz = fsig(aZ[1]);
            const float nn = ftanh(aNX[1] + rr * (aNH[1] + bnh));
            ho1 = nn + zz * (ho1 - nn);
            hL[nxt][r0 + 1][uc + lc] = (f16)ho1;
        }
        {
            const float rr = fsig(aR[2]), zz = fsig(aZ[2]);
            const float nn = ftanh(aNX[2] + rr * (aNH[2] + bnh));
            ho2 = nn + zz * (ho2 - nn);
            hL[nxt][r0 + 2][uc + lc] = (f16)ho2;
        }
        {
            const float rr = fsig(aR[3]), zz = fsig(aZ[3]);
            const float nn = ftanh(aNX[3] + rr * (aNH[3] + bnh));
            ho3 = nn + zz * (ho3 - nn);
            hL[nxt][r0 + 3][uc + lc] = (f16)ho3;
        }
        __syncthreads();   // nxt-buffer h complete; cur buffer free for overwrite next step
    };

    for (int s = 0; s < S_N; s += 2) {
        step(s,     xsA);
        step(s + 1, xsB);
    }

    // ---------------- epilogue ----------------
    {
        const int r0 = lg * 4;
        hfL[r0 + 0][uc + lc] = ho0;
        hfL[r0 + 1][uc + lc] = ho1;
        hfL[r0 + 2][uc + lc] = ho2;
        hfL[r0 + 3][uc + lc] = ho3;
    }

    // backward cell: single step from h0=0 (=> Whh_b unused), on x[:, S-1, :]
    {
        const int row2 = tid >> 4;          // 0..15
        const int j0   = (tid & 15) * 4;    // 4 units per thread
        const float* wib = Wih_b + (size_t)t * G3 * I_N;
        const float* bib = bih_b + t * G3;
        const float* bhb = bhh_b + t * G3;
        float xr[I_N];
        #pragma unroll
        for (int k = 0; k < I_N; ++k)
            xr[k] = x[(((size_t)(b0 + row2) * S_N + (S_N - 1)) * T_N + t) * I_N + k];
        #pragma unroll
        for (int m = 0; m < 4; ++m) {
            const int j = j0 + m;
            float ir = bib[j], iz = bib[64 + j], inn = bib[128 + j];
            #pragma unroll
            for (int k = 0; k < I_N; ++k) {
                const float xv = xr[k];
                ir  += wib[(size_t)j * I_N + k]          * xv;
                iz  += wib[(size_t)(64 + j) * I_N + k]   * xv;
                inn += wib[(size_t)(128 + j) * I_N + k]  * xv;
            }
            const float r  = fsig(ir + bhb[j]);
            const float z  = fsig(iz + bhb[64 + j]);
            const float nn = ftanh(inn + r * bhb[128 + j]);
            hbL[row2][j] = (1.0f - z) * nn;   // h0 = 0
        }
    }
    __syncthreads();

    // FC: out[b,0,t] = [hf|hb] . Wfc[t,0,:] + bfc[t]
    if (tid < BT) {
        const float* wfc = Wfc + (size_t)t * 2 * H_N;
        float acc = bfc[t];
        #pragma unroll 4
        for (int j = 0; j < H_N; ++j) acc += hfL[tid][j] * wfc[j];
        #pragma unroll 4
        for (int j = 0; j < H_N; ++j) acc += hbL[tid][j] * wfc[64 + j];
        out[(size_t)(b0 + tid) * T_N + t] = acc;
    }
}

extern "C" void kernel_launch(void* const* d_in, const int* in_sizes, int n_in,
                              void* d_out, int out_size, void* d_ws, size_t ws_size,
                              hipStream_t stream) {
    const float* x     = (const float*)d_in[0];
    const float* Wih_f = (const float*)d_in[1];
    const float* Whh_f = (const float*)d_in[2];
    const float* bih_f = (const float*)d_in[3];
    const float* bhh_f = (const float*)d_in[4];
    const float* Wih_b = (const float*)d_in[5];
    // d_in[6] = Whh_b: unused (backward cell runs one step from h0 == 0).
    const float* bih_b = (const float*)d_in[7];
    const float* bhh_b = (const float*)d_in[8];
    const float* Wfc   = (const float*)d_in[9];
    const float* bfc   = (const float*)d_in[10];
    float* out = (float*)d_out;

    dim3 grid(T_N * NB), block(256);
    hipLaunchKernelGGL(gru_mfma, grid, block, 0, stream,
                       x, Wih_f, Whh_f, bih_f, bhh_f, Wih_b, bih_b, bhh_b, Wfc, bfc, out);
}

// Round 4
// 118.906 us; speedup vs baseline: 7.8691x; 1.5221x over previous
//
#include <hip/hip_runtime.h>

// GRU via MFMA, round 4: B=128, S=144, T=50, I=10, H=64, O=1.
// Grid = T * (B/16) = 400 wgs x 256 threads (4 waves).
// Wave w owns gate-cols uc=w*16 (r/z/n tiles) over the wg's 16 batch rows.
// Weights+biases resident in VGPRs; x prefetched depth-2 into NAMED float2
// registers (R3's lambda/struct version spilled to scratch: WRITE_SIZE 3.2MB);
// h round-trips through double-buffered f16 LDS, one barrier per step.
// Gates via v_exp_f32 / v_rcp_f32.
//
// MFMA 16x16x32 f16 layouts (gfx950, m89-verified):
//   A: m=lane&15, k=(lane>>4)*8+e;  B: n=lane&15, same k-map;
//   D: col=lane&15, row=(lane>>4)*4+reg.

typedef _Float16 f16;
typedef _Float16 f16x8 __attribute__((ext_vector_type(8)));
typedef float    f32x4 __attribute__((ext_vector_type(4)));

constexpr int B_N = 128, S_N = 144, T_N = 50, I_N = 10, H_N = 64, G3 = 192;
constexpr int BT = 16, NB = B_N / BT;   // 8 batch tiles
constexpr int HST = 88;                 // f16/row -> 176B; ds_read_b128 2-way max (free)

#define MFMA16(a, b, c) __builtin_amdgcn_mfma_f32_16x16x32_f16((a), (b), (c), 0, 0, 0)

__device__ __forceinline__ float fsig(float v) {
    return __builtin_amdgcn_rcpf(1.0f + __builtin_amdgcn_exp2f(-1.44269504089f * v));
}
__device__ __forceinline__ float ftanh(float v) {
    return 1.0f - 2.0f * __builtin_amdgcn_rcpf(1.0f + __builtin_amdgcn_exp2f(2.88539008178f * v));
}

// ---- per-step macros: everything stays in named registers (no struct, no lambda) ----

// issue x loads for step (ss) into named float2 regs (lg0: q0..q3, lg1: q4)
#define LOADX(ss, q0, q1, q2, q3, q4)                                             \
    if ((ss) < S_N) {                                                             \
        const float* _p = x + (((size_t)(b0 + lc) * S_N + (ss)) * T_N + t) * I_N; \
        if (lg == 0) {                                                            \
            q0 = *(const float2*)(_p);     q1 = *(const float2*)(_p + 2);         \
            q2 = *(const float2*)(_p + 4); q3 = *(const float2*)(_p + 6);         \
        } else if (lg == 1) {                                                     \
            q4 = *(const float2*)(_p + 8);                                        \
        }                                                                         \
    }

#define STEP(ss, q0, q1, q2, q3, q4)                                              \
    {                                                                             \
        const int cur = (ss) & 1, nxt = cur ^ 1;                                  \
        const f16* hrow = &hL[cur][lc][0];                                        \
        const f16x8 hA0 = *(const f16x8*)(hrow + lg * 8);                         \
        const f16x8 hA1 = *(const f16x8*)(hrow + 32 + lg * 8);                    \
        f16x8 xA;                                                                 \
        _Pragma("unroll")                                                         \
        for (int e = 0; e < 8; ++e) xA[e] = (f16)0.0f;                            \
        if (lg == 0) {                                                            \
            xA[0] = (f16)q0.x; xA[1] = (f16)q0.y; xA[2] = (f16)q1.x; xA[3] = (f16)q1.y; \
            xA[4] = (f16)q2.x; xA[5] = (f16)q2.y; xA[6] = (f16)q3.x; xA[7] = (f16)q3.y; \
        } else if (lg == 1) {                                                     \
            xA[0] = (f16)q4.x; xA[1] = (f16)q4.y; xA[2] = (f16)1.0f;              \
        }                                                                         \
        LOADX((ss) + 2, q0, q1, q2, q3, q4)                                       \
        f32x4 aR  = {0.f, 0.f, 0.f, 0.f};                                         \
        f32x4 aZ  = {0.f, 0.f, 0.f, 0.f};                                         \
        f32x4 aNH = {0.f, 0.f, 0.f, 0.f};                                         \
        f32x4 aNX = {0.f, 0.f, 0.f, 0.f};                                         \
        aR  = MFMA16(xA,  BxR,  aR);                                              \
        aZ  = MFMA16(xA,  BxZ,  aZ);                                              \
        aNX = MFMA16(xA,  BxN,  aNX);                                             \
        aR  = MFMA16(hA0, BhR0, aR);                                              \
        aR  = MFMA16(hA1, BhR1, aR);                                              \
        aZ  = MFMA16(hA0, BhZ0, aZ);                                              \
        aZ  = MFMA16(hA1, BhZ1, aZ);                                              \
        aNH = MFMA16(hA0, BhN0, aNH);                                             \
        aNH = MFMA16(hA1, BhN1, aNH);                                             \
        const int r0 = lg * 4;                                                    \
        {                                                                         \
            const float rr = fsig(aR[0]), zz = fsig(aZ[0]);                       \
            const float nn = ftanh(aNX[0] + rr * (aNH[0] + bnh));                 \
            ho0 = nn + zz * (ho0 - nn);                                           \
            hL[nxt][r0 + 0][uc + lc] = (f16)ho0;                                  \
        }                                                                         \
        {                                                                         \
            const float rr = fsig(aR[1]), zz = fsig(aZ[1]);                       \
            const float nn = ftanh(aNX[1] + rr * (aNH[1] + bnh));                 \
            ho1 = nn + zz * (ho1 - nn);                                           \
            hL[nxt][r0 + 1][uc + lc] = (f16)ho1;                                  \
        }                                                                         \
        {                                                                         \
            const float rr = fsig(aR[2]), zz = fsig(aZ[2]);                       \
            const float nn = ftanh(aNX[2] + rr * (aNH[2] + bnh));                 \
            ho2 = nn + zz * (ho2 - nn);                                           \
            hL[nxt][r0 + 2][uc + lc] = (f16)ho2;                                  \
        }                                                                         \
        {                                                                         \
            const float rr = fsig(aR[3]), zz = fsig(aZ[3]);                       \
            const float nn = ftanh(aNX[3] + rr * (aNH[3] + bnh));                 \
            ho3 = nn + zz * (ho3 - nn);                                           \
            hL[nxt][r0 + 3][uc + lc] = (f16)ho3;                                  \
        }                                                                         \
        __syncthreads();                                                          \
    }

__global__ __launch_bounds__(256, 2)
void gru_mfma(const float* __restrict__ x,
              const float* __restrict__ Wih_f, const float* __restrict__ Whh_f,
              const float* __restrict__ bih_f, const float* __restrict__ bhh_f,
              const float* __restrict__ Wih_b, const float* __restrict__ bih_b,
              const float* __restrict__ bhh_b,
              const float* __restrict__ Wfc,   const float* __restrict__ bfc,
              float* __restrict__ out)
{
    __shared__ f16   hL[2][BT][HST];        // 5.6 KB double-buffered h (f16)
    __shared__ float hfL[BT][H_N + 1];      // epilogue: forward h (f32)
    __shared__ float hbL[BT][H_N + 1];      // epilogue: backward h (f32)

    const int tid = threadIdx.x;
    const int w   = tid >> 6, l = tid & 63;
    const int uc  = w * 16;            // unit-col base 0,16,32,48
    const int lc  = l & 15;            // n (gate col) for B/D; m (batch row) for A
    const int lg  = l >> 4;            // k-group
    const int t   = blockIdx.x / NB;
    const int b0  = (blockIdx.x % NB) * BT;

    // ---------------- prologue ----------------
    {
        f16* hp = &hL[0][0][0];
        for (int i = tid; i < BT * HST; i += 256) hp[i] = (f16)0.0f;   // h0 = 0
    }

    const float* Whh = Whh_f + (size_t)t * G3 * H_N;
    const float* Wih = Wih_f + (size_t)t * G3 * I_N;

    auto loadBh = [&](int g, int kk) -> f16x8 {
        const float4* p = (const float4*)(Whh + (size_t)g * H_N + kk * 32 + lg * 8);
        const float4 a = p[0], b = p[1];
        f16x8 v;
        v[0] = (f16)a.x; v[1] = (f16)a.y; v[2] = (f16)a.z; v[3] = (f16)a.w;
        v[4] = (f16)b.x; v[5] = (f16)b.y; v[6] = (f16)b.z; v[7] = (f16)b.w;
        return v;
    };
    auto loadBx = [&](int g, bool rz) -> f16x8 {
        f16x8 v;
        #pragma unroll
        for (int j = 0; j < 8; ++j) {
            const int k = lg * 8 + j;
            float val = 0.0f;
            if (k < I_N)       val = Wih[(size_t)g * I_N + k];
            else if (k == 10)  val = bih_f[t * G3 + g] + (rz ? bhh_f[t * G3 + g] : 0.0f);
            v[j] = (f16)val;
        }
        return v;
    };

    const f16x8 BhR0 = loadBh(uc + lc, 0),       BhR1 = loadBh(uc + lc, 1);
    const f16x8 BhZ0 = loadBh(64 + uc + lc, 0),  BhZ1 = loadBh(64 + uc + lc, 1);
    const f16x8 BhN0 = loadBh(128 + uc + lc, 0), BhN1 = loadBh(128 + uc + lc, 1);
    const f16x8 BxR  = loadBx(uc + lc, true);
    const f16x8 BxZ  = loadBx(64 + uc + lc, true);
    const f16x8 BxN  = loadBx(128 + uc + lc, false);
    const float bnh  = bhh_f[t * G3 + 128 + uc + lc];

    // x prefetch registers (named scalars -> never spilled to scratch)
    float2 xa0 = {0.f,0.f}, xa1 = {0.f,0.f}, xa2 = {0.f,0.f}, xa3 = {0.f,0.f}, xa4 = {0.f,0.f};
    float2 xb0 = {0.f,0.f}, xb1 = {0.f,0.f}, xb2 = {0.f,0.f}, xb3 = {0.f,0.f}, xb4 = {0.f,0.f};
    LOADX(0, xa0, xa1, xa2, xa3, xa4)
    LOADX(1, xb0, xb1, xb2, xb3, xb4)

    float ho0 = 0.f, ho1 = 0.f, ho2 = 0.f, ho3 = 0.f;   // lane's h: rows lg*4+j, col uc+lc

    __syncthreads();

    // ---------------- scan ----------------
    for (int s = 0; s < S_N; s += 2) {
        STEP(s,     xa0, xa1, xa2, xa3, xa4)
        STEP(s + 1, xb0, xb1, xb2, xb3, xb4)
    }

    // ---------------- epilogue ----------------
    {
        const int r0 = lg * 4;
        hfL[r0 + 0][uc + lc] = ho0;
        hfL[r0 + 1][uc + lc] = ho1;
        hfL[r0 + 2][uc + lc] = ho2;
        hfL[r0 + 3][uc + lc] = ho3;
    }

    // backward cell: single step from h0=0 (=> Whh_b unused), on x[:, S-1, :]
    {
        const int row2 = tid >> 4;          // 0..15
        const int j0   = (tid & 15) * 4;    // 4 units per thread
        const float* wib = Wih_b + (size_t)t * G3 * I_N;
        const float* bib = bih_b + t * G3;
        const float* bhb = bhh_b + t * G3;
        float xr[I_N];
        #pragma unroll
        for (int k = 0; k < I_N; ++k)
            xr[k] = x[(((size_t)(b0 + row2) * S_N + (S_N - 1)) * T_N + t) * I_N + k];
        #pragma unroll
        for (int m = 0; m < 4; ++m) {
            const int j = j0 + m;
            float ir = bib[j], iz = bib[64 + j], inn = bib[128 + j];
            #pragma unroll
            for (int k = 0; k < I_N; ++k) {
                const float xv = xr[k];
                ir  += wib[(size_t)j * I_N + k]          * xv;
                iz  += wib[(size_t)(64 + j) * I_N + k]   * xv;
                inn += wib[(size_t)(128 + j) * I_N + k]  * xv;
            }
            const float r  = fsig(ir + bhb[j]);
            const float z  = fsig(iz + bhb[64 + j]);
            const float nn = ftanh(inn + r * bhb[128 + j]);
            hbL[row2][j] = (1.0f - z) * nn;   // h0 = 0
        }
    }
    __syncthreads();

    // FC: out[b,0,t] = [hf|hb] . Wfc[t,0,:] + bfc[t]
    if (tid < BT) {
        const float* wfc = Wfc + (size_t)t * 2 * H_N;
        float acc = bfc[t];
        #pragma unroll 4
        for (int j = 0; j < H_N; ++j) acc += hfL[tid][j] * wfc[j];
        #pragma unroll 4
        for (int j = 0; j < H_N; ++j) acc += hbL[tid][j] * wfc[64 + j];
        out[(size_t)(b0 + tid) * T_N + t] = acc;
    }
}

extern "C" void kernel_launch(void* const* d_in, const int* in_sizes, int n_in,
                              void* d_out, int out_size, void* d_ws, size_t ws_size,
                              hipStream_t stream) {
    const float* x     = (const float*)d_in[0];
    const float* Wih_f = (const float*)d_in[1];
    const float* Whh_f = (const float*)d_in[2];
    const float* bih_f = (const float*)d_in[3];
    const float* bhh_f = (const float*)d_in[4];
    const float* Wih_b = (const float*)d_in[5];
    // d_in[6] = Whh_b: unused (backward cell runs one step from h0 == 0).
    const float* bih_b = (const float*)d_in[7];
    const float* bhh_b = (const float*)d_in[8];
    const float* Wfc   = (const float*)d_in[9];
    const float* bfc   = (const float*)d_in[10];
    float* out = (float*)d_out;

    dim3 grid(T_N * NB), block(256);
    hipLaunchKernelGGL(gru_mfma, grid, block, 0, stream,
                       x, Wih_f, Whh_f, bih_f, bhh_f, Wih_b, bih_b, bhh_b, Wfc, bfc, out);
}

// Round 5
// 102.441 us; speedup vs baseline: 9.1338x; 1.1607x over previous
//
#include <hip/hip_runtime.h>

// GRU via MFMA, round 5: B=128, S=144, T=50, I=10, H=64, O=1.
// Grid = T * (B/16) = 400 wgs x 256 threads (4 waves).
// vs R4: (1) raw s_barrier (no vmcnt drain -> x prefetch stays in flight),
// (2) x pre-packed to f16 fragment layout by a prep kernel (no per-step cvt),
// (3) weights pre-scaled by -log2e (r,z) / 2log2e (n) so exp2 args come
// straight from the MFMA accumulators.
//
// MFMA 16x16x32 f16 layouts (gfx950, m89-verified):
//   A: m=lane&15, k=(lane>>4)*8+e;  B: n=lane&15, same k-map;
//   D: col=lane&15, row=(lane>>4)*4+reg.

typedef _Float16 f16;
typedef _Float16 f16x8 __attribute__((ext_vector_type(8)));
typedef float    f32x4 __attribute__((ext_vector_type(4)));

constexpr int B_N = 128, S_N = 144, T_N = 50, I_N = 10, H_N = 64, G3 = 192;
constexpr int BT = 16, NB = B_N / BT;   // 8 batch tiles
constexpr int HST = 88;                 // f16/row -> 176B; ds_read_b128 2-way max (free)
constexpr float L2E = 1.44269504089f;

#define MFMA16(a, b, c) __builtin_amdgcn_mfma_f32_16x16x32_f16((a), (b), (c), 0, 0, 0)

__device__ __forceinline__ float fsig(float v) {   // epilogue only
    return __builtin_amdgcn_rcpf(1.0f + __builtin_amdgcn_exp2f(-L2E * v));
}
__device__ __forceinline__ float ftanh(float v) {  // epilogue only
    return 1.0f - 2.0f * __builtin_amdgcn_rcpf(1.0f + __builtin_amdgcn_exp2f(2.0f * L2E * v));
}

// ---- x prep: xP[(b*S+s)*T+t][16] f16 = {x[0..9], 1.0, 0,0,0,0,0} (A-fragment rows) ----
__global__ __launch_bounds__(256)
void pack_x(const float* __restrict__ x, f16* __restrict__ xP) {
    const int idx = blockIdx.x * 256 + threadIdx.x;
    if (idx >= B_N * S_N * T_N) return;
    const float* s = x + (size_t)idx * I_N;
    f16x8 lo, hi;
    #pragma unroll
    for (int e = 0; e < 8; ++e) lo[e] = (f16)s[e];
    hi[0] = (f16)s[8]; hi[1] = (f16)s[9]; hi[2] = (f16)1.0f;
    #pragma unroll
    for (int e = 3; e < 8; ++e) hi[e] = (f16)0.0f;
    f16* d = xP + (size_t)idx * 16;
    *(f16x8*)d = lo; *(f16x8*)(d + 8) = hi;
}

// x prefetch (packed path): one masked 16B load, directly MFMA-usable
#define LOADX_P(ss, xf)                                                           \
    if ((ss) < S_N && lg < 2)                                                     \
        xf = *(const f16x8*)(xProw + (size_t)(ss) * (T_N * 16) + lg * 8);

// x prefetch (raw fallback): float2 loads into named regs, packed at use
#define LOADX_R(ss, q0, q1, q2, q3, q4)                                           \
    if ((ss) < S_N) {                                                             \
        const float* _p = x + (((size_t)(b0 + lc) * S_N + (ss)) * T_N + t) * I_N; \
        if (lg == 0) {                                                            \
            q0 = *(const float2*)(_p);     q1 = *(const float2*)(_p + 2);         \
            q2 = *(const float2*)(_p + 4); q3 = *(const float2*)(_p + 6);         \
        } else if (lg == 1) {                                                     \
            q4 = *(const float2*)(_p + 8);                                        \
        }                                                                         \
    }

#define STEP(ss, xf, q0, q1, q2, q3, q4)                                          \
    {                                                                             \
        const int cur = (ss) & 1, nxt = cur ^ 1;                                  \
        const f16* hrow = &hL[cur][lc][0];                                        \
        const f16x8 hA0 = *(const f16x8*)(hrow + lg * 8);                         \
        const f16x8 hA1 = *(const f16x8*)(hrow + 32 + lg * 8);                    \
        f16x8 xA;                                                                 \
        if constexpr (PX) {                                                       \
            xA = xf;                                                              \
            LOADX_P((ss) + 2, xf)                                                 \
        } else {                                                                  \
            _Pragma("unroll")                                                     \
            for (int e = 0; e < 8; ++e) xA[e] = (f16)0.0f;                        \
            if (lg == 0) {                                                        \
                xA[0] = (f16)q0.x; xA[1] = (f16)q0.y; xA[2] = (f16)q1.x; xA[3] = (f16)q1.y; \
                xA[4] = (f16)q2.x; xA[5] = (f16)q2.y; xA[6] = (f16)q3.x; xA[7] = (f16)q3.y; \
            } else if (lg == 1) {                                                 \
                xA[0] = (f16)q4.x; xA[1] = (f16)q4.y; xA[2] = (f16)1.0f;          \
            }                                                                     \
            LOADX_R((ss) + 2, q0, q1, q2, q3, q4)                                 \
        }                                                                         \
        f32x4 aR  = {0.f, 0.f, 0.f, 0.f};                                         \
        f32x4 aZ  = {0.f, 0.f, 0.f, 0.f};                                         \
        f32x4 aNH = {0.f, 0.f, 0.f, 0.f};                                         \
        f32x4 aNX = {0.f, 0.f, 0.f, 0.f};                                         \
        aR  = MFMA16(xA,  BxR,  aR);                                              \
        aZ  = MFMA16(xA,  BxZ,  aZ);                                              \
        aNX = MFMA16(xA,  BxN,  aNX);                                             \
        aR  = MFMA16(hA0, BhR0, aR);                                              \
        aR  = MFMA16(hA1, BhR1, aR);                                              \
        aZ  = MFMA16(hA0, BhZ0, aZ);                                              \
        aZ  = MFMA16(hA1, BhZ1, aZ);                                              \
        aNH = MFMA16(hA0, BhN0, aNH);                                             \
        aNH = MFMA16(hA1, BhN1, aNH);                                             \
        const int r0 = lg * 4;                                                    \
        _Pragma("unroll")                                                         \
        for (int j = 0; j < 4; ++j) {                                             \
            const float rr = __builtin_amdgcn_rcpf(1.0f + __builtin_amdgcn_exp2f(aR[j])); \
            const float zz = __builtin_amdgcn_rcpf(1.0f + __builtin_amdgcn_exp2f(aZ[j])); \
            const float qq = __builtin_amdgcn_rcpf(1.0f + __builtin_amdgcn_exp2f(fmaf(rr, aNH[j] + bnhs, aNX[j]))); \
            const float nn = fmaf(-2.0f, qq, 1.0f);                               \
            ho[j] = fmaf(zz, ho[j] - nn, nn);                                     \
            hL[nxt][r0 + j][uc + lc] = (f16)ho[j];                                \
        }                                                                         \
        asm volatile("s_waitcnt lgkmcnt(0)" ::: "memory");                        \
        __builtin_amdgcn_s_barrier();                                             \
        asm volatile("" ::: "memory");                                            \
    }

template<bool PX>
__global__ __launch_bounds__(256, 2)
void gru_mfma(const float* __restrict__ x, const f16* __restrict__ xP,
              const float* __restrict__ Wih_f, const float* __restrict__ Whh_f,
              const float* __restrict__ bih_f, const float* __restrict__ bhh_f,
              const float* __restrict__ Wih_b, const float* __restrict__ bih_b,
              const float* __restrict__ bhh_b,
              const float* __restrict__ Wfc,   const float* __restrict__ bfc,
              float* __restrict__ out)
{
    __shared__ f16   hL[2][BT][HST];        // 5.6 KB double-buffered h (f16)
    __shared__ float hfL[BT][H_N + 1];      // epilogue: forward h (f32)
    __shared__ float hbL[BT][H_N + 1];      // epilogue: backward h (f32)

    const int tid = threadIdx.x;
    const int w   = tid >> 6, l = tid & 63;
    const int uc  = w * 16;            // unit-col base 0,16,32,48
    const int lc  = l & 15;            // n (gate col) for B/D; m (batch row) for A
    const int lg  = l >> 4;            // k-group
    const int t   = blockIdx.x / NB;
    const int b0  = (blockIdx.x % NB) * BT;

    // ---------------- prologue ----------------
    {
        f16* hp = &hL[0][0][0];
        for (int i = tid; i < BT * HST; i += 256) hp[i] = (f16)0.0f;   // h0 = 0
    }

    const float* Whh = Whh_f + (size_t)t * G3 * H_N;
    const float* Wih = Wih_f + (size_t)t * G3 * I_N;
    const f16*  xProw = PX ? (xP + ((size_t)(b0 + lc) * S_N * T_N + t) * 16) : nullptr;

    // weight fragments, pre-scaled: r,z by -log2e; n by +2log2e
    const float sRZ = -L2E, sN = 2.0f * L2E;
    auto loadBh = [&](int g, int kk, float sc) -> f16x8 {
        const float4* p = (const float4*)(Whh + (size_t)g * H_N + kk * 32 + lg * 8);
        const float4 a = p[0], b = p[1];
        f16x8 v;
        v[0] = (f16)(sc * a.x); v[1] = (f16)(sc * a.y); v[2] = (f16)(sc * a.z); v[3] = (f16)(sc * a.w);
        v[4] = (f16)(sc * b.x); v[5] = (f16)(sc * b.y); v[6] = (f16)(sc * b.z); v[7] = (f16)(sc * b.w);
        return v;
    };
    auto loadBx = [&](int g, bool rz, float sc) -> f16x8 {
        f16x8 v;
        #pragma unroll
        for (int j = 0; j < 8; ++j) {
            const int k = lg * 8 + j;
            float val = 0.0f;
            if (k < I_N)       val = Wih[(size_t)g * I_N + k];
            else if (k == 10)  val = bih_f[t * G3 + g] + (rz ? bhh_f[t * G3 + g] : 0.0f);
            v[j] = (f16)(sc * val);
        }
        return v;
    };

    const f16x8 BhR0 = loadBh(uc + lc, 0, sRZ),        BhR1 = loadBh(uc + lc, 1, sRZ);
    const f16x8 BhZ0 = loadBh(64 + uc + lc, 0, sRZ),   BhZ1 = loadBh(64 + uc + lc, 1, sRZ);
    const f16x8 BhN0 = loadBh(128 + uc + lc, 0, sN),   BhN1 = loadBh(128 + uc + lc, 1, sN);
    const f16x8 BxR  = loadBx(uc + lc, true, sRZ);
    const f16x8 BxZ  = loadBx(64 + uc + lc, true, sRZ);
    const f16x8 BxN  = loadBx(128 + uc + lc, false, sN);
    const float bnhs = sN * bhh_f[t * G3 + 128 + uc + lc];

    // x prefetch registers (both paths declared; unused set folds away)
    f16x8 xpA, xpB;
    #pragma unroll
    for (int e = 0; e < 8; ++e) { xpA[e] = (f16)0.0f; xpB[e] = (f16)0.0f; }
    float2 ra0 = {0.f,0.f}, ra1 = {0.f,0.f}, ra2 = {0.f,0.f}, ra3 = {0.f,0.f}, ra4 = {0.f,0.f};
    float2 rb0 = {0.f,0.f}, rb1 = {0.f,0.f}, rb2 = {0.f,0.f}, rb3 = {0.f,0.f}, rb4 = {0.f,0.f};
    if constexpr (PX) {
        LOADX_P(0, xpA)
        LOADX_P(1, xpB)
    } else {
        LOADX_R(0, ra0, ra1, ra2, ra3, ra4)
        LOADX_R(1, rb0, rb1, rb2, rb3, rb4)
    }

    float ho[4] = {0.f, 0.f, 0.f, 0.f};   // lane's h: rows lg*4+j, col uc+lc

    __syncthreads();

    // ---------------- scan ----------------
    for (int s = 0; s < S_N; s += 2) {
        STEP(s,     xpA, ra0, ra1, ra2, ra3, ra4)
        STEP(s + 1, xpB, rb0, rb1, rb2, rb3, rb4)
    }

    // ---------------- epilogue ----------------
    {
        const int r0 = lg * 4;
        hfL[r0 + 0][uc + lc] = ho[0];
        hfL[r0 + 1][uc + lc] = ho[1];
        hfL[r0 + 2][uc + lc] = ho[2];
        hfL[r0 + 3][uc + lc] = ho[3];
    }

    // backward cell: single step from h0=0 (=> Whh_b unused), on x[:, S-1, :]
    {
        const int row2 = tid >> 4;          // 0..15
        const int j0   = (tid & 15) * 4;    // 4 units per thread
        const float* wib = Wih_b + (size_t)t * G3 * I_N;
        const float* bib = bih_b + t * G3;
        const float* bhb = bhh_b + t * G3;
        float xr[I_N];
        #pragma unroll
        for (int k = 0; k < I_N; ++k)
            xr[k] = x[(((size_t)(b0 + row2) * S_N + (S_N - 1)) * T_N + t) * I_N + k];
        #pragma unroll
        for (int m = 0; m < 4; ++m) {
            const int j = j0 + m;
            float ir = bib[j], iz = bib[64 + j], inn = bib[128 + j];
            #pragma unroll
            for (int k = 0; k < I_N; ++k) {
                const float xv = xr[k];
                ir  += wib[(size_t)j * I_N + k]          * xv;
                iz  += wib[(size_t)(64 + j) * I_N + k]   * xv;
                inn += wib[(size_t)(128 + j) * I_N + k]  * xv;
            }
            const float r  = fsig(ir + bhb[j]);
            const float z  = fsig(iz + bhb[64 + j]);
            const float nn = ftanh(inn + r * bhb[128 + j]);
            hbL[row2][j] = (1.0f - z) * nn;   // h0 = 0
        }
    }
    __syncthreads();

    // FC: out[b,0,t] = [hf|hb] . Wfc[t,0,:] + bfc[t]
    if (tid < BT) {
        const float* wfc = Wfc + (size_t)t * 2 * H_N;
        float acc = bfc[t];
        #pragma unroll 4
        for (int j = 0; j < H_N; ++j) acc += hfL[tid][j] * wfc[j];
        #pragma unroll 4
        for (int j = 0; j < H_N; ++j) acc += hbL[tid][j] * wfc[64 + j];
        out[(size_t)(b0 + tid) * T_N + t] = acc;
    }
}

extern "C" void kernel_launch(void* const* d_in, const int* in_sizes, int n_in,
                              void* d_out, int out_size, void* d_ws, size_t ws_size,
                              hipStream_t stream) {
    const float* x     = (const float*)d_in[0];
    const float* Wih_f = (const float*)d_in[1];
    const float* Whh_f = (const float*)d_in[2];
    const float* bih_f = (const float*)d_in[3];
    const float* bhh_f = (const float*)d_in[4];
    const float* Wih_b = (const float*)d_in[5];
    // d_in[6] = Whh_b: unused (backward cell runs one step from h0 == 0).
    const float* bih_b = (const float*)d_in[7];
    const float* bhh_b = (const float*)d_in[8];
    const float* Wfc   = (const float*)d_in[9];
    const float* bfc   = (const float*)d_in[10];
    float* out = (float*)d_out;

    const size_t xp_bytes = (size_t)B_N * S_N * T_N * 16 * sizeof(f16);  // 29.5 MB
    dim3 grid(T_N * NB), block(256);

    if (ws_size >= xp_bytes) {
        f16* xP = (f16*)d_ws;
        const int n = B_N * S_N * T_N;
        hipLaunchKernelGGL(pack_x, dim3((n + 255) / 256), dim3(256), 0, stream, x, xP);
        hipLaunchKernelGGL((gru_mfma<true>), grid, block, 0, stream,
                           x, xP, Wih_f, Whh_f, bih_f, bhh_f, Wih_b, bih_b, bhh_b, Wfc, bfc, out);
    } else {
        hipLaunchKernelGGL((gru_mfma<false>), grid, block, 0, stream,
                           x, nullptr, Wih_f, Whh_f, bih_f, bhh_f, Wih_b, bih_b, bhh_b, Wfc, bfc, out);
    }
}